// Round 1
// baseline (516.115 us; speedup 1.0000x reference)
//
#include <hip/hip_runtime.h>
#include <math.h>

#define HW 512
#define MASK 511
#define IMG (512*512)
#define NSTEP 16
#define NSLICE 17

#define TILE_Y 128
#define TILE_X 64
#define IN_Y (TILE_Y + 20)   // 148
#define IN_X (TILE_X + 20)   // 84

// LDS word address: row stride 84 plus 12 extra words every 4 rows.
// Keeps 16B alignment (all terms mult of 4) and spreads the 4-row stride
// across all 32 banks (inter-ty stride = 4*84+12 = 348 words == 28 mod 32,
// an odd 16B-granule phase -> uniform bank usage on ds_read_b128).
__device__ __forceinline__ int lds_word(int r, int c) {
    return r * 84 + ((r >> 2) * 12) + c;
}
#define LDS_WORDS (147*84 + 36*12 + 84)   // 12864 words = 50.25 KiB

__global__ void prep_kernel(const float* __restrict__ w1,
                            const float* __restrict__ w2,
                            const float* __restrict__ w3,
                            float* __restrict__ ws) {
    int i = threadIdx.x;
    // wpad[27][21]: rows 3..23 hold w1 rows 0..20, rest zero (dy in [-3,23] guard-free)
    for (int idx = i; idx < 27 * 21; idx += blockDim.x) {
        int dyp = idx / 21;
        int dx  = idx - dyp * 21;
        int dy  = dyp - 3;
        float v = 0.f;
        if (dy >= 0 && dy <= 20) v = w1[dy * 21 + dx];
        ws[idx] = v;
    }
    if (i == 0) {
        // MLP collapses: C = sum_o w3[o] * max(w2[o], 0)   (valid since h >= 0)
        float c = 0.f;
        for (int o = 0; o < 10; ++o) c += w3[o] * fmaxf(w2[o], 0.f);
        ws[567] = c;
    }
}

__global__ void copy_kernel(const float* __restrict__ x, float* __restrict__ out) {
    int i = blockIdx.x * blockDim.x + threadIdx.x;   // float4 index
    if (i < 8 * 65536) {
        const float4* in4 = (const float4*)x;
        float4* out4 = (float4*)out;
        int b = i >> 16;
        int off = i & 65535;
        out4[(size_t)b * (NSLICE * 65536) + off] = in4[i];
    }
}

__global__ __launch_bounds__(256, 1)
void step_kernel(const float* __restrict__ state_base,
                 float* __restrict__ out_base,
                 const float* __restrict__ ws,
                 int t) {
    __shared__ float tile[LDS_WORDS];
    const int tx = threadIdx.x;        // 0..7
    const int ty = threadIdx.y;        // 0..31
    const int tid = tx + (ty << 3);
    const int X0 = blockIdx.x * TILE_X;
    const int Y0 = blockIdx.y * TILE_Y;
    const int b  = blockIdx.z;

    const float* __restrict__ in  = state_base + (size_t)(b * NSLICE + (t - 1)) * IMG;
    float* __restrict__ outp      = out_base   + (size_t)(b * NSLICE + t) * IMG;

    // stage 148x84 input tile with circular wrap
    for (int idx = tid; idx < IN_Y * IN_X; idx += 256) {
        int r = idx / IN_X;
        int c = idx - r * IN_X;
        int gr = (Y0 + r - 10) & MASK;
        int gc = (X0 + c - 10) & MASK;
        tile[lds_word(r, c)] = in[gr * HW + gc];
    }
    __syncthreads();

    const int R0 = ty << 2;   // 4 output rows per thread
    const int C0 = tx << 3;   // 8 output cols per thread

    float acc[4][8];
    #pragma unroll
    for (int a = 0; a < 4; ++a)
        #pragma unroll
        for (int cc = 0; cc < 8; ++cc) acc[a][cc] = 0.f;

    // scatter over 24 input rows: each row window loaded once, feeds 4 output rows
    for (int rr = 0; rr < 24; ++rr) {
        float win[28];
        #pragma unroll
        for (int k = 0; k < 7; ++k) {
            float4 v = *(const float4*)&tile[lds_word(R0 + rr, C0 + 4 * k)];
            win[4*k+0] = v.x; win[4*k+1] = v.y; win[4*k+2] = v.z; win[4*k+3] = v.w;
        }
        #pragma unroll
        for (int ro = 0; ro < 4; ++ro) {
            const float* __restrict__ wrow = ws + (rr + 3 - ro) * 21;  // dyp = rr-ro+3
            #pragma unroll
            for (int dx = 0; dx < 21; ++dx) {
                float w = wrow[dx];
                #pragma unroll
                for (int cc = 0; cc < 8; ++cc)
                    acc[ro][cc] = fmaf(w, win[dx + cc], acc[ro][cc]);
            }
        }
    }

    const float C = ws[567];
    #pragma unroll
    for (int ro = 0; ro < 4; ++ro) {
        float res[8];
        #pragma unroll
        for (int cc = 0; cc < 8; ++cc) {
            float xv = tile[lds_word(R0 + ro + 10, C0 + cc + 10)];
            float a  = xv + C * fmaxf(acc[ro][cc], 0.f);
            float ax = fabsf(a);
            float e  = __expf(2.f * ax);                       // tanh(|a|) = 1 - 2/(e+1)
            float r  = 1.f - 2.f * __builtin_amdgcn_rcpf(e + 1.f);
            res[cc]  = copysignf(r, a);
        }
        int row = Y0 + R0 + ro;
        float4* po = (float4*)&outp[(size_t)row * HW + X0 + C0];
        po[0] = make_float4(res[0], res[1], res[2], res[3]);
        po[1] = make_float4(res[4], res[5], res[6], res[7]);
    }
}

extern "C" void kernel_launch(void* const* d_in, const int* in_sizes, int n_in,
                              void* d_out, int out_size, void* d_ws, size_t ws_size,
                              hipStream_t stream) {
    const float* x  = (const float*)d_in[0];
    const float* w1 = (const float*)d_in[1];
    const float* w2 = (const float*)d_in[2];
    const float* w3 = (const float*)d_in[3];
    float* out = (float*)d_out;
    float* ws  = (float*)d_ws;

    prep_kernel<<<1, 128, 0, stream>>>(w1, w2, w3, ws);
    copy_kernel<<<2048, 256, 0, stream>>>(x, out);

    dim3 grid(HW / TILE_X, HW / TILE_Y, 8);   // 8 x 4 x 8 = 256 blocks
    dim3 block(8, 32);
    for (int t = 1; t <= NSTEP; ++t)          // steps = 16 (fixed by setup_inputs)
        step_kernel<<<grid, block, 0, stream>>>(out, out, ws, t);
}

// Round 2
// 442.840 us; speedup vs baseline: 1.1655x; 1.1655x over previous
//
#include <hip/hip_runtime.h>
#include <math.h>

#define HW 512
#define MASK 511
#define IMG (512*512)
#define NSTEP 16
#define NSLICE 17

#define TILE_Y 32
#define TILE_X 64
#define IN_Y 52            // 32 + 20 halo
#define IN_X 84            // 64 + 20 halo
#define LDS_WORDS (IN_Y * IN_X)   // 4368 words = 17.06 KiB
// LDS layout is plain linear [r*84 + c]: granule stride per row = 21 (odd),
// so 8 consecutive ty-lanes hit all 8 16B bank-groups -> free 2-way on b128.

__global__ void prep_kernel(const float* __restrict__ w2,
                            const float* __restrict__ w3,
                            float* __restrict__ ws) {
    if (threadIdx.x == 0) {
        // 1->10->1 MLP on a nonnegative scalar collapses:
        // sum_o w3[o]*relu(w2[o]*h) = h * sum_o w3[o]*max(w2[o],0)  for h>=0
        float c = 0.f;
        for (int o = 0; o < 10; ++o) c += w3[o] * fmaxf(w2[o], 0.f);
        ws[0] = c;
    }
}

__global__ void copy_kernel(const float* __restrict__ x, float* __restrict__ out) {
    int i = blockIdx.x * blockDim.x + threadIdx.x;   // float4 index
    if (i < 8 * 65536) {
        const float4* in4 = (const float4*)x;
        float4* out4 = (float4*)out;
        int b = i >> 16;
        int off = i & 65535;
        out4[(size_t)b * (NSLICE * 65536) + off] = in4[i];
    }
}

__global__ __launch_bounds__(256, 4)
void step_kernel(const float* __restrict__ state_base,
                 float* __restrict__ out_base,
                 const float* __restrict__ w1,
                 const float* __restrict__ ws,
                 int t) {
    __shared__ float tile[LDS_WORDS];
    const int tx = threadIdx.x;        // 0..7  -> 8 cols each
    const int ty = threadIdx.y;        // 0..31 -> 1 row each
    const int tid = tx + (ty << 3);
    const int X0 = blockIdx.x * TILE_X;
    const int Y0 = blockIdx.y * TILE_Y;
    const int b  = blockIdx.z;

    const float* __restrict__ in  = state_base + (size_t)(b * NSLICE + (t - 1)) * IMG;
    float* __restrict__ outp      = out_base   + (size_t)(b * NSLICE + t) * IMG;

    // stage 52x84 input tile with circular wrap; LDS layout linear -> addr = idx
    for (int idx = tid; idx < IN_Y * IN_X; idx += 256) {
        int r = idx / IN_X;
        int c = idx - r * IN_X;
        int gr = (Y0 + r - 10) & MASK;
        int gc = (X0 + c - 10) & MASK;
        tile[idx] = in[gr * HW + gc];
    }
    __syncthreads();

    const int C0 = tx << 3;

    float acc[8];
    #pragma unroll
    for (int cc = 0; cc < 8; ++cc) acc[cc] = 0.f;
    float ctr[8];
    #pragma unroll
    for (int cc = 0; cc < 8; ++cc) ctr[cc] = 0.f;

    // gather: out row (Y0+ty); dy == rr, each weight row fetched once (uniform s_load)
    for (int rr = 0; rr < 21; ++rr) {
        float win[28];
        const float* trow = &tile[(ty + rr) * IN_X + C0];
        #pragma unroll
        for (int k = 0; k < 7; ++k) {
            float4 v = *(const float4*)&trow[4 * k];
            win[4*k+0] = v.x; win[4*k+1] = v.y; win[4*k+2] = v.z; win[4*k+3] = v.w;
        }
        if (rr == 10) {   // center row: residual x values live in win[10..17]
            #pragma unroll
            for (int cc = 0; cc < 8; ++cc) ctr[cc] = win[10 + cc];
        }
        const float* __restrict__ wrow = w1 + rr * 21;
        #pragma unroll
        for (int dx = 0; dx < 21; ++dx) {
            float w = wrow[dx];
            #pragma unroll
            for (int cc = 0; cc < 8; ++cc)
                acc[cc] = fmaf(w, win[dx + cc], acc[cc]);
        }
    }

    const float C = ws[0];
    float res[8];
    #pragma unroll
    for (int cc = 0; cc < 8; ++cc) {
        float a  = ctr[cc] + C * fmaxf(acc[cc], 0.f);
        float ax = fabsf(a);
        float e  = __expf(2.f * ax);                      // tanh(|a|) = 1 - 2/(e+1)
        float r  = 1.f - 2.f * __builtin_amdgcn_rcpf(e + 1.f);
        res[cc]  = copysignf(r, a);
    }
    int row = Y0 + ty;
    float4* po = (float4*)&outp[(size_t)row * HW + X0 + C0];
    po[0] = make_float4(res[0], res[1], res[2], res[3]);
    po[1] = make_float4(res[4], res[5], res[6], res[7]);
}

extern "C" void kernel_launch(void* const* d_in, const int* in_sizes, int n_in,
                              void* d_out, int out_size, void* d_ws, size_t ws_size,
                              hipStream_t stream) {
    const float* x  = (const float*)d_in[0];
    const float* w1 = (const float*)d_in[1];
    const float* w2 = (const float*)d_in[2];
    const float* w3 = (const float*)d_in[3];
    float* out = (float*)d_out;
    float* ws  = (float*)d_ws;

    prep_kernel<<<1, 64, 0, stream>>>(w2, w3, ws);
    copy_kernel<<<2048, 256, 0, stream>>>(x, out);

    dim3 grid(HW / TILE_X, HW / TILE_Y, 8);   // 8 x 16 x 8 = 1024 blocks = 4/CU
    dim3 block(8, 32);
    for (int t = 1; t <= NSTEP; ++t)          // steps = 16 (fixed by setup_inputs)
        step_kernel<<<grid, block, 0, stream>>>(out, out, w1, ws, t);
}